// Round 6
// baseline (398.525 us; speedup 1.0000x reference)
//
#include <hip/hip_runtime.h>
#include <hip/hip_bf16.h>

#define CDIM 64
#define KCODES 512
#define HWD 4096          // H*W
#define NPIX 131072       // B*H*W
#define NELEM 8388608     // B*C*H*W
#define BLK 128           // threads per block (2 waves); xs = 128*65*4 = 33.3 KB LDS
// out layout (fp32 elements): [0]=loss, [1..1+NELEM)=quantized,
// then enc_idx(NPIX), perplexity(1), codes(NPIX)
#define OFF_Q 1
#define OFF_ENC (1 + NELEM)
#define OFF_PERP (1 + NELEM + NPIX)
#define OFF_CODES (1 + NELEM + NPIX + 1)

// numpy pairwise_sum for n=64 of separately-rounded squares of v[0..63]
__device__ __forceinline__ float np_pairwise_combine8(const float* r) {
    float s01 = __fadd_rn(r[0], r[1]);
    float s23 = __fadd_rn(r[2], r[3]);
    float s45 = __fadd_rn(r[4], r[5]);
    float s67 = __fadd_rn(r[6], r[7]);
    return __fadd_rn(__fadd_rn(s01, s23), __fadd_rn(s45, s67));
}

__device__ __forceinline__ float np_pairwise_sq64(const float* v) {
    float r[8];
    #pragma unroll
    for (int j = 0; j < 8; ++j) r[j] = __fmul_rn(v[j], v[j]);
    #pragma unroll
    for (int i = 8; i < 64; i += 8) {
        #pragma unroll
        for (int j = 0; j < 8; ++j) r[j] = __fadd_rn(r[j], __fmul_rn(v[i + j], v[i + j]));
    }
    return np_pairwise_combine8(r);
}

// ws float layout: [0]=loss_acc, [64..576)=counts, [576..1088)=ee
__global__ void ee_kernel(const float* __restrict__ e, float* __restrict__ ee) {
    int k = blockIdx.x * blockDim.x + threadIdx.x;
    if (k < KCODES) {
        float v[CDIM];
        #pragma unroll
        for (int c = 0; c < CDIM; ++c) v[c] = e[k * CDIM + c];
        ee[k] = np_pairwise_sq64(v);
    }
}

// Each thread owns one pixel. x-row lives in LDS (private row, stride 65 ->
// 2-way bank alias = free), NOT in registers: round-4/5 showed LLVM remats a
// 64-live register array into per-k-group global reloads (VGPR=44, VALU 40%).
// e-operands are wave-uniform -> scalar loads; inner loop is pure v_fmac with
// one SGPR operand each. 8 codes/k-group: 512 FMA per 64 ds_read_b32.
__launch_bounds__(BLK, 1)
__global__ void vq_main(const float* __restrict__ in, const float* __restrict__ e,
                        const float* __restrict__ ee, float* __restrict__ loss_acc,
                        float* __restrict__ counts, float* __restrict__ out) {
    __shared__ float xs[BLK][65];
    int tid = threadIdx.x;
    int p = blockIdx.x * BLK + tid;
    int b = p >> 12;          // p / HWD
    int hw = p & (HWD - 1);

    const float* xin = in + (size_t)b * CDIM * HWD + hw;

    // stage x into LDS + compute xx (numpy pairwise-8 of rounded squares)
    float r[8];
    #pragma unroll
    for (int j = 0; j < 8; ++j) {
        float t = xin[(size_t)j * HWD];
        xs[tid][j] = t;
        r[j] = __fmul_rn(t, t);
    }
    #pragma unroll
    for (int i = 8; i < 64; i += 8) {
        #pragma unroll
        for (int j = 0; j < 8; ++j) {
            float t = xin[(size_t)(i + j) * HWD];
            xs[tid][i + j] = t;
            r[j] = __fadd_rn(r[j], __fmul_rn(t, t));
        }
    }
    float xx = np_pairwise_combine8(r);

    float dmin = 3.4e38f;
    int idx = 0;
    for (int kg = 0; kg < KCODES; kg += 8) {
        const float* e0 = e + (size_t)kg * CDIM;
        float d0 = 0.f, d1 = 0.f, d2 = 0.f, d3 = 0.f;
        float d4 = 0.f, d5 = 0.f, d6 = 0.f, d7 = 0.f;
        #pragma unroll
        for (int c = 0; c < CDIM; ++c) {
            float xc = xs[tid][c];
            d0 = __fmaf_rn(xc, e0[c], d0);
            d1 = __fmaf_rn(xc, e0[1 * CDIM + c], d1);
            d2 = __fmaf_rn(xc, e0[2 * CDIM + c], d2);
            d3 = __fmaf_rn(xc, e0[3 * CDIM + c], d3);
            d4 = __fmaf_rn(xc, e0[4 * CDIM + c], d4);
            d5 = __fmaf_rn(xc, e0[5 * CDIM + c], d5);
            d6 = __fmaf_rn(xc, e0[6 * CDIM + c], d6);
            d7 = __fmaf_rn(xc, e0[7 * CDIM + c], d7);
        }
        float dd;
        dd = __fsub_rn(__fadd_rn(xx, ee[kg + 0]), __fmul_rn(2.f, d0)); if (dd < dmin) { dmin = dd; idx = kg + 0; }
        dd = __fsub_rn(__fadd_rn(xx, ee[kg + 1]), __fmul_rn(2.f, d1)); if (dd < dmin) { dmin = dd; idx = kg + 1; }
        dd = __fsub_rn(__fadd_rn(xx, ee[kg + 2]), __fmul_rn(2.f, d2)); if (dd < dmin) { dmin = dd; idx = kg + 2; }
        dd = __fsub_rn(__fadd_rn(xx, ee[kg + 3]), __fmul_rn(2.f, d3)); if (dd < dmin) { dmin = dd; idx = kg + 3; }
        dd = __fsub_rn(__fadd_rn(xx, ee[kg + 4]), __fmul_rn(2.f, d4)); if (dd < dmin) { dmin = dd; idx = kg + 4; }
        dd = __fsub_rn(__fadd_rn(xx, ee[kg + 5]), __fmul_rn(2.f, d5)); if (dd < dmin) { dmin = dd; idx = kg + 5; }
        dd = __fsub_rn(__fadd_rn(xx, ee[kg + 6]), __fmul_rn(2.f, d6)); if (dd < dmin) { dmin = dd; idx = kg + 6; }
        dd = __fsub_rn(__fadd_rn(xx, ee[kg + 7]), __fmul_rn(2.f, d7)); if (dd < dmin) { dmin = dd; idx = kg + 7; }
    }

    // quantized output (fp32) + latent-loss partial; x re-read from LDS
    const float4* eq = reinterpret_cast<const float4*>(e + (size_t)idx * CDIM);
    float* outq = out + OFF_Q + (size_t)b * CDIM * HWD + hw;
    float lsum = 0.f;
    #pragma unroll
    for (int j = 0; j < 16; ++j) {
        float4 q = eq[j];
        int c = 4 * j;
        outq[(size_t)(c + 0) * HWD] = q.x;
        outq[(size_t)(c + 1) * HWD] = q.y;
        outq[(size_t)(c + 2) * HWD] = q.z;
        outq[(size_t)(c + 3) * HWD] = q.w;
        float t0 = q.x - xs[tid][c + 0];
        float t1 = q.y - xs[tid][c + 1];
        float t2 = q.z - xs[tid][c + 2];
        float t3 = q.w - xs[tid][c + 3];
        lsum = fmaf(t0, t0, lsum);
        lsum = fmaf(t1, t1, lsum);
        lsum = fmaf(t2, t2, lsum);
        lsum = fmaf(t3, t3, lsum);
    }

    float fidx = (float)idx;
    out[OFF_ENC + p] = fidx;
    out[OFF_CODES + p] = fidx;

    atomicAdd(&counts[idx], 1.0f);

    // wave-reduce loss partial (wave = 64)
    #pragma unroll
    for (int off = 32; off > 0; off >>= 1) lsum += __shfl_down(lsum, off, 64);
    if ((threadIdx.x & 63) == 0) atomicAdd(loss_acc, lsum);
}

__global__ void finalize_kernel(const float* __restrict__ loss_acc,
                                const float* __restrict__ counts,
                                float* __restrict__ out) {
    __shared__ float red[8];
    int t = threadIdx.x;  // 512 threads
    float pr = counts[t] * (1.0f / (float)NPIX);
    float term = pr * logf(pr + 1e-10f);
    #pragma unroll
    for (int off = 32; off > 0; off >>= 1) term += __shfl_down(term, off, 64);
    if ((t & 63) == 0) red[t >> 6] = term;
    __syncthreads();
    if (t == 0) {
        float s = 0.f;
        #pragma unroll
        for (int i = 0; i < 8; ++i) s += red[i];
        out[OFF_PERP] = expf(-s);
        out[0] = 0.25f * loss_acc[0] * (1.0f / (float)NELEM);
    }
}

extern "C" void kernel_launch(void* const* d_in, const int* in_sizes, int n_in,
                              void* d_out, int out_size, void* d_ws, size_t ws_size,
                              hipStream_t stream) {
    const float* in = (const float*)d_in[0];
    const float* e = (const float*)d_in[1];
    float* out = (float*)d_out;
    float* wsf = (float*)d_ws;
    float* loss_acc = wsf + 0;
    float* counts = wsf + 64;
    float* ee = wsf + 576;

    hipMemsetAsync(d_ws, 0, 2304, stream);  // loss_acc + counts
    ee_kernel<<<1, 512, 0, stream>>>(e, ee);
    vq_main<<<NPIX / BLK, BLK, 0, stream>>>(in, e, ee, loss_acc, counts, out);
    finalize_kernel<<<1, 512, 0, stream>>>(loss_acc, counts, out);
}

// Round 7
// 339.809 us; speedup vs baseline: 1.1728x; 1.1728x over previous
//
#include <hip/hip_runtime.h>
#include <hip/hip_bf16.h>

#define CDIM 64
#define KCODES 512
#define HWD 4096          // H*W
#define NPIX 131072       // B*H*W
#define NELEM 8388608     // B*C*H*W
#define BLK 128           // 2 waves; e-stage = 128 thr * 16B = 2KB = one 8-code group
#define NKG (KCODES / 8)  // 64 k-groups
// out layout (fp32 elements): [0]=loss, [1..1+NELEM)=quantized,
// then enc_idx(NPIX), perplexity(1), codes(NPIX)
#define OFF_Q 1
#define OFF_ENC (1 + NELEM)
#define OFF_PERP (1 + NELEM + NPIX)
#define OFF_CODES (1 + NELEM + NPIX + 1)

// numpy pairwise combine of 8 partials
__device__ __forceinline__ float np_pairwise_combine8(const float* r) {
    float s01 = __fadd_rn(r[0], r[1]);
    float s23 = __fadd_rn(r[2], r[3]);
    float s45 = __fadd_rn(r[4], r[5]);
    float s67 = __fadd_rn(r[6], r[7]);
    return __fadd_rn(__fadd_rn(s01, s23), __fadd_rn(s45, s67));
}

__device__ __forceinline__ float np_pairwise_sq64(const float* v) {
    float r[8];
    #pragma unroll
    for (int j = 0; j < 8; ++j) r[j] = __fmul_rn(v[j], v[j]);
    #pragma unroll
    for (int i = 8; i < 64; i += 8) {
        #pragma unroll
        for (int j = 0; j < 8; ++j) r[j] = __fadd_rn(r[j], __fmul_rn(v[i + j], v[i + j]));
    }
    return np_pairwise_combine8(r);
}

// ws float layout: [0]=loss_acc, [64..576)=counts, [576..1088)=ee
__global__ void ee_kernel(const float* __restrict__ e, float* __restrict__ ee) {
    int k = blockIdx.x * blockDim.x + threadIdx.x;
    if (k < KCODES) {
        float v[CDIM];
        #pragma unroll
        for (int c = 0; c < CDIM; ++c) v[c] = e[k * CDIM + c];
        ee[k] = np_pairwise_sq64(v);
    }
}

// Rounds 4-6 all showed VALUBusy ~38-40% regardless of x-handling: the
// bottleneck is e-delivery via wave-uniform s_loads (16KB K$, ~320B SGPR
// chunks, lgkmcnt stall per chunk). Fix: double-buffered LDS staging of the
// 2KB e k-group (global_load issued BEFORE compute, ds_write after), inner
// loop reads e via broadcast ds_read_b128 (conflict-free, co-issues with
// VALU). x[64] pinned in VGPRs via asm so LLVM can't remat the loads.
__launch_bounds__(BLK, 1)
__global__ void vq_main(const float* __restrict__ in, const float* __restrict__ e,
                        const float* __restrict__ ee, float* __restrict__ loss_acc,
                        float* __restrict__ counts, float* __restrict__ out) {
    __shared__ float elds[2][512];
    int tid = threadIdx.x;
    int p = blockIdx.x * BLK + tid;
    int b = p >> 12;          // p / HWD
    int hw = p & (HWD - 1);

    const float* xin = in + (size_t)b * CDIM * HWD + hw;

    // load x + xx (numpy pairwise-8 of rounded squares)
    float x[CDIM];
    float r[8];
    #pragma unroll
    for (int j = 0; j < 8; ++j) {
        x[j] = xin[(size_t)j * HWD];
        r[j] = __fmul_rn(x[j], x[j]);
    }
    #pragma unroll
    for (int i = 8; i < 64; i += 8) {
        #pragma unroll
        for (int j = 0; j < 8; ++j) {
            x[i + j] = xin[(size_t)(i + j) * HWD];
            r[j] = __fadd_rn(r[j], __fmul_rn(x[i + j], x[i + j]));
        }
    }
    float xx = np_pairwise_combine8(r);

    // pin x into VGPRs (prevents remat of the strided global loads into the loop)
    #pragma unroll
    for (int i = 0; i < 64; i += 8)
        asm volatile("" : "+v"(x[i]), "+v"(x[i+1]), "+v"(x[i+2]), "+v"(x[i+3]),
                          "+v"(x[i+4]), "+v"(x[i+5]), "+v"(x[i+6]), "+v"(x[i+7]));

    // prologue: stage k-group 0
    {
        float4 ev = *reinterpret_cast<const float4*>(e + (size_t)tid * 4);
        *reinterpret_cast<float4*>(&elds[0][tid * 4]) = ev;
    }
    __syncthreads();

    float dmin = 3.4e38f;
    int idx = 0;
    for (int kg = 0; kg < NKG; ++kg) {
        int cur = kg & 1;
        int nkg = (kg + 1) & (NKG - 1);   // wraps to 0 on last iter (harmless re-stage)
        // issue next group's global load BEFORE compute (latency hides under FMAs)
        float4 enext = *reinterpret_cast<const float4*>(e + (size_t)nkg * 512 + tid * 4);

        const float* eb = elds[cur];
        float d0 = 0.f, d1 = 0.f, d2 = 0.f, d3 = 0.f;
        float d4 = 0.f, d5 = 0.f, d6 = 0.f, d7 = 0.f;
        #pragma unroll
        for (int cb = 0; cb < CDIM; cb += 4) {
            float4 e0 = *reinterpret_cast<const float4*>(&eb[0 * 64 + cb]);
            float4 e1 = *reinterpret_cast<const float4*>(&eb[1 * 64 + cb]);
            float4 e2 = *reinterpret_cast<const float4*>(&eb[2 * 64 + cb]);
            float4 e3 = *reinterpret_cast<const float4*>(&eb[3 * 64 + cb]);
            float4 e4 = *reinterpret_cast<const float4*>(&eb[4 * 64 + cb]);
            float4 e5 = *reinterpret_cast<const float4*>(&eb[5 * 64 + cb]);
            float4 e6 = *reinterpret_cast<const float4*>(&eb[6 * 64 + cb]);
            float4 e7 = *reinterpret_cast<const float4*>(&eb[7 * 64 + cb]);
            // accumulation order per code: c ascending — matches reference chain
            d0 = __fmaf_rn(x[cb], e0.x, d0); d0 = __fmaf_rn(x[cb+1], e0.y, d0);
            d0 = __fmaf_rn(x[cb+2], e0.z, d0); d0 = __fmaf_rn(x[cb+3], e0.w, d0);
            d1 = __fmaf_rn(x[cb], e1.x, d1); d1 = __fmaf_rn(x[cb+1], e1.y, d1);
            d1 = __fmaf_rn(x[cb+2], e1.z, d1); d1 = __fmaf_rn(x[cb+3], e1.w, d1);
            d2 = __fmaf_rn(x[cb], e2.x, d2); d2 = __fmaf_rn(x[cb+1], e2.y, d2);
            d2 = __fmaf_rn(x[cb+2], e2.z, d2); d2 = __fmaf_rn(x[cb+3], e2.w, d2);
            d3 = __fmaf_rn(x[cb], e3.x, d3); d3 = __fmaf_rn(x[cb+1], e3.y, d3);
            d3 = __fmaf_rn(x[cb+2], e3.z, d3); d3 = __fmaf_rn(x[cb+3], e3.w, d3);
            d4 = __fmaf_rn(x[cb], e4.x, d4); d4 = __fmaf_rn(x[cb+1], e4.y, d4);
            d4 = __fmaf_rn(x[cb+2], e4.z, d4); d4 = __fmaf_rn(x[cb+3], e4.w, d4);
            d5 = __fmaf_rn(x[cb], e5.x, d5); d5 = __fmaf_rn(x[cb+1], e5.y, d5);
            d5 = __fmaf_rn(x[cb+2], e5.z, d5); d5 = __fmaf_rn(x[cb+3], e5.w, d5);
            d6 = __fmaf_rn(x[cb], e6.x, d6); d6 = __fmaf_rn(x[cb+1], e6.y, d6);
            d6 = __fmaf_rn(x[cb+2], e6.z, d6); d6 = __fmaf_rn(x[cb+3], e6.w, d6);
            d7 = __fmaf_rn(x[cb], e7.x, d7); d7 = __fmaf_rn(x[cb+1], e7.y, d7);
            d7 = __fmaf_rn(x[cb+2], e7.z, d7); d7 = __fmaf_rn(x[cb+3], e7.w, d7);
        }
        int k0 = kg * 8;
        float dd;
        dd = __fsub_rn(__fadd_rn(xx, ee[k0 + 0]), __fmul_rn(2.f, d0)); if (dd < dmin) { dmin = dd; idx = k0 + 0; }
        dd = __fsub_rn(__fadd_rn(xx, ee[k0 + 1]), __fmul_rn(2.f, d1)); if (dd < dmin) { dmin = dd; idx = k0 + 1; }
        dd = __fsub_rn(__fadd_rn(xx, ee[k0 + 2]), __fmul_rn(2.f, d2)); if (dd < dmin) { dmin = dd; idx = k0 + 2; }
        dd = __fsub_rn(__fadd_rn(xx, ee[k0 + 3]), __fmul_rn(2.f, d3)); if (dd < dmin) { dmin = dd; idx = k0 + 3; }
        dd = __fsub_rn(__fadd_rn(xx, ee[k0 + 4]), __fmul_rn(2.f, d4)); if (dd < dmin) { dmin = dd; idx = k0 + 4; }
        dd = __fsub_rn(__fadd_rn(xx, ee[k0 + 5]), __fmul_rn(2.f, d5)); if (dd < dmin) { dmin = dd; idx = k0 + 5; }
        dd = __fsub_rn(__fadd_rn(xx, ee[k0 + 6]), __fmul_rn(2.f, d6)); if (dd < dmin) { dmin = dd; idx = k0 + 6; }
        dd = __fsub_rn(__fadd_rn(xx, ee[k0 + 7]), __fmul_rn(2.f, d7)); if (dd < dmin) { dmin = dd; idx = k0 + 7; }

        // write next group into the other buffer (vmcnt wait lands here, after compute)
        *reinterpret_cast<float4*>(&elds[cur ^ 1][tid * 4]) = enext;
        __syncthreads();
    }

    // quantized output (fp32) + latent-loss partial (x from pinned regs)
    const float4* eq = reinterpret_cast<const float4*>(e + (size_t)idx * CDIM);
    float* outq = out + OFF_Q + (size_t)b * CDIM * HWD + hw;
    float lsum = 0.f;
    #pragma unroll
    for (int j = 0; j < 16; ++j) {
        float4 q = eq[j];
        int c = 4 * j;
        outq[(size_t)(c + 0) * HWD] = q.x;
        outq[(size_t)(c + 1) * HWD] = q.y;
        outq[(size_t)(c + 2) * HWD] = q.z;
        outq[(size_t)(c + 3) * HWD] = q.w;
        float t0 = q.x - x[c + 0];
        float t1 = q.y - x[c + 1];
        float t2 = q.z - x[c + 2];
        float t3 = q.w - x[c + 3];
        lsum = fmaf(t0, t0, lsum);
        lsum = fmaf(t1, t1, lsum);
        lsum = fmaf(t2, t2, lsum);
        lsum = fmaf(t3, t3, lsum);
    }

    float fidx = (float)idx;
    out[OFF_ENC + p] = fidx;
    out[OFF_CODES + p] = fidx;

    atomicAdd(&counts[idx], 1.0f);

    // wave-reduce loss partial (wave = 64)
    #pragma unroll
    for (int off = 32; off > 0; off >>= 1) lsum += __shfl_down(lsum, off, 64);
    if ((threadIdx.x & 63) == 0) atomicAdd(loss_acc, lsum);
}

__global__ void finalize_kernel(const float* __restrict__ loss_acc,
                                const float* __restrict__ counts,
                                float* __restrict__ out) {
    __shared__ float red[8];
    int t = threadIdx.x;  // 512 threads
    float pr = counts[t] * (1.0f / (float)NPIX);
    float term = pr * logf(pr + 1e-10f);
    #pragma unroll
    for (int off = 32; off > 0; off >>= 1) term += __shfl_down(term, off, 64);
    if ((t & 63) == 0) red[t >> 6] = term;
    __syncthreads();
    if (t == 0) {
        float s = 0.f;
        #pragma unroll
        for (int i = 0; i < 8; ++i) s += red[i];
        out[OFF_PERP] = expf(-s);
        out[0] = 0.25f * loss_acc[0] * (1.0f / (float)NELEM);
    }
}

extern "C" void kernel_launch(void* const* d_in, const int* in_sizes, int n_in,
                              void* d_out, int out_size, void* d_ws, size_t ws_size,
                              hipStream_t stream) {
    const float* in = (const float*)d_in[0];
    const float* e = (const float*)d_in[1];
    float* out = (float*)d_out;
    float* wsf = (float*)d_ws;
    float* loss_acc = wsf + 0;
    float* counts = wsf + 64;
    float* ee = wsf + 576;

    hipMemsetAsync(d_ws, 0, 2304, stream);  // loss_acc + counts
    ee_kernel<<<1, 512, 0, stream>>>(e, ee);
    vq_main<<<NPIX / BLK, BLK, 0, stream>>>(in, e, ee, loss_acc, counts, out);
    finalize_kernel<<<1, 512, 0, stream>>>(loss_acc, counts, out);
}